// Round 3
// baseline (465.059 us; speedup 1.0000x reference)
//
#include <hip/hip_runtime.h>

#define HW 65536
#define CDIM 512
#define NN 50
#define NROWS 51

__device__ __forceinline__ float wave_sum(float v) {
#pragma unroll
  for (int off = 32; off; off >>= 1) v += __shfl_xor(v, off, 64);
  return v;
}
__device__ __forceinline__ int wave_sum_i(int v) {
#pragma unroll
  for (int off = 32; off; off >>= 1) v += __shfl_xor(v, off, 64);
  return v;
}
__device__ __forceinline__ float wave_max(float v) {
#pragma unroll
  for (int off = 32; off; off >>= 1) v = fmaxf(v, __shfl_xor(v, off, 64));
  return v;
}
__device__ __forceinline__ int wave_max_i(int v) {
#pragma unroll
  for (int off = 32; off; off >>= 1) v = max(v, __shfl_xor(v, off, 64));
  return v;
}
__device__ __forceinline__ int wave_min_i(int v) {
#pragma unroll
  for (int off = 32; off; off >>= 1) v = min(v, __shfl_xor(v, off, 64));
  return v;
}

// ---- P0: mask counts + zero seg + zero barriers -------------------------
__global__ __launch_bounds__(256) void k_prep(const int* __restrict__ msk,
                                              int* __restrict__ blkcnt,
                                              float* __restrict__ seg,
                                              int* __restrict__ bar) {
  int t = threadIdx.x, b = blockIdx.x;
  int g = b * 256 + t;
  if (g < NN * CDIM) seg[g] = 0.f;
  int g2 = g + 16384;
  if (g2 < NN * CDIM) seg[g2] = 0.f;
  if (b == 0 && t < 8) bar[t] = 0;
  int4 m = ((const int4*)msk)[g];
  int c = (m.x != 0) + (m.y != 0) + (m.z != 0) + (m.w != 0);
  c = wave_sum_i(c);
  __shared__ int wl[4];
  if ((t & 63) == 0) wl[t >> 6] = c;
  __syncthreads();
  if (t == 0) blkcnt[b] = wl[0] + wl[1] + wl[2] + wl[3];
}

// ---- P1: scan (redundant per block) + per-pixel bins + boundary px ------
// meta: [0]=L, [52..101]=cnt, [102..151]=extra-pixel flag
__global__ __launch_bounds__(256) void k_rank(const int* __restrict__ msk,
                                              const int* __restrict__ blkcnt,
                                              int* __restrict__ meta,
                                              unsigned char* __restrict__ bin8,
                                              int* __restrict__ P) {
  int t = threadIdx.x, blk = blockIdx.x;
  __shared__ int sblkoff, sL;
  __shared__ int sst[NN + 1];
  __shared__ int wtot[4];
  if (t < 64) {
    int c = blkcnt[t];
    int x = c;
#pragma unroll
    for (int d = 1; d < 64; d <<= 1) {
      int y = __shfl_up(x, d, 64);
      if (t >= d) x += y;
    }
    if (t == blk) sblkoff = x - c;
    if (t == 63) sL = x;
  }
  __syncthreads();
  int L = sL;
  if (t <= NN) sst[t] = (int)((long long)t * L / NN);
  if (blk == 0 && t < NN) {
    if (t == 0) meta[0] = L;
    long long Ll = L;
    int s = (int)((long long)t * Ll / NN);
    int e = (int)(((long long)(t + 1) * Ll + NN - 1) / NN);
    int ci = (int)(((long long)t * Ll + NN - 1) / NN);
    meta[2 + NN + t] = e - s;
    meta[2 + 2 * NN + t] = (t >= 1 && ci > s) ? 1 : 0;
  }
  int4 m = ((const int4*)msk)[blk * 256 + t];
  int fl[4] = {m.x != 0, m.y != 0, m.z != 0, m.w != 0};
  int cnt = fl[0] + fl[1] + fl[2] + fl[3];
  int lane = t & 63, wv = t >> 6;
  int x = cnt;
#pragma unroll
  for (int d = 1; d < 64; d <<= 1) {
    int y = __shfl_up(x, d, 64);
    if (lane >= d) x += y;
  }
  if (lane == 63) wtot[wv] = x;
  __syncthreads();
  int base = sblkoff + (x - cnt);
  for (int w = 0; w < wv; ++w) base += wtot[w];
  int p0 = blk * 1024 + t * 4;
  int r = base;
#pragma unroll
  for (int j = 0; j < 4; ++j) {
    int p = p0 + j;
    unsigned char bv = 255;
    if (fl[j]) {
      int bi = (int)((long long)NN * r / L);
      bv = (unsigned char)bi;
      if (sst[bi] == r) P[bi] = p;
      if (bi + 1 < NN && sst[bi + 1] == r) P[bi + 1] = p;
      r++;
    }
    bin8[p] = bv;
  }
}

// ---- P2: heavy streaming pass — segment sums ----------------------------
// 512-px windows; bins are contiguous rank-ranges -> per-window span<=1 for
// L >= 50*512; masks as 0/1 floats -> pure FMA inner loop.
__global__ __launch_bounds__(256) void k_seg(const float* __restrict__ fts,
                                             const unsigned char* __restrict__ bin8,
                                             float* __restrict__ seg) {
  int pb = blockIdx.x * 512;
  int t = threadIdx.x, lane = t & 63, wv = t >> 6;
  int cw = blockIdx.y * 64 + wv * 16;
  uchar4 u0 = *(const uchar4*)(bin8 + pb + lane * 4);
  uchar4 u1 = *(const uchar4*)(bin8 + pb + 256 + lane * 4);
  int bb[8] = {u0.x, u0.y, u0.z, u0.w, u1.x, u1.y, u1.z, u1.w};
  int mn = 255, mx = -1;
#pragma unroll
  for (int j = 0; j < 8; ++j)
    if (bb[j] != 255) { mn = min(mn, bb[j]); mx = max(mx, bb[j]); }
  mn = wave_min_i(mn);
  mx = wave_max_i(mx);
  if (mx < 0) return;
  int span = mx - mn;
  const float* base = fts + (size_t)cw * HW + pb + lane * 4;
  if (span <= 1) {
    float mlo[8], mhi[8];
#pragma unroll
    for (int j = 0; j < 8; ++j) {
      mlo[j] = (bb[j] == mn) ? 1.f : 0.f;
      mhi[j] = (bb[j] == mx) ? 1.f : 0.f;
    }
    float alo[16], ahi[16];
#pragma unroll
    for (int cs = 0; cs < 16; ++cs) { alo[cs] = 0.f; ahi[cs] = 0.f; }
    if (span == 0) {
#pragma unroll 4
      for (int cs = 0; cs < 16; ++cs) {
        const float* p = base + (size_t)cs * HW;
        float4 v0 = *(const float4*)p;
        float4 v1 = *(const float4*)(p + 256);
        alo[cs] = v0.x * mlo[0] + v0.y * mlo[1] + v0.z * mlo[2] + v0.w * mlo[3] +
                  v1.x * mlo[4] + v1.y * mlo[5] + v1.z * mlo[6] + v1.w * mlo[7];
      }
    } else {
#pragma unroll 4
      for (int cs = 0; cs < 16; ++cs) {
        const float* p = base + (size_t)cs * HW;
        float4 v0 = *(const float4*)p;
        float4 v1 = *(const float4*)(p + 256);
        alo[cs] = v0.x * mlo[0] + v0.y * mlo[1] + v0.z * mlo[2] + v0.w * mlo[3] +
                  v1.x * mlo[4] + v1.y * mlo[5] + v1.z * mlo[6] + v1.w * mlo[7];
        ahi[cs] = v0.x * mhi[0] + v0.y * mhi[1] + v0.z * mhi[2] + v0.w * mhi[3] +
                  v1.x * mhi[4] + v1.y * mhi[5] + v1.z * mhi[6] + v1.w * mhi[7];
      }
    }
#pragma unroll 1
    for (int cs = 0; cs < 16; ++cs) {
      float s = wave_sum(alo[cs]);
      if (lane == 0 && s != 0.f) atomicAdd(&seg[mn * CDIM + cw + cs], s);
    }
    if (span == 1) {
#pragma unroll 1
      for (int cs = 0; cs < 16; ++cs) {
        float s = wave_sum(ahi[cs]);
        if (lane == 0 && s != 0.f) atomicAdd(&seg[mx * CDIM + cw + cs], s);
      }
    }
  } else {
    // pathological fallback (span > 1): per-pixel atomics, correct but slow
#pragma unroll 1
    for (int cs = 0; cs < 16; ++cs) {
      const float* p = base + (size_t)cs * HW;
      float4 v0 = *(const float4*)p;
      float4 v1 = *(const float4*)(p + 256);
      float vs[8] = {v0.x, v0.y, v0.z, v0.w, v1.x, v1.y, v1.z, v1.w};
#pragma unroll
      for (int j = 0; j < 8; ++j)
        if (bb[j] != 255) atomicAdd(&seg[bb[j] * CDIM + cw + cs], vs[j]);
    }
  }
}

// ---- grid barrier (agent scope, single-use slots zeroed in k_prep) ------
__device__ __forceinline__ void gbar(int* bar, int id, int nblk) {
  __syncthreads();
  if (threadIdx.x == 0) {
    __hip_atomic_fetch_add(&bar[id], 1, __ATOMIC_ACQ_REL, __HIP_MEMORY_SCOPE_AGENT);
    while (__hip_atomic_load(&bar[id], __ATOMIC_ACQUIRE, __HIP_MEMORY_SCOPE_AGENT) < nblk)
      __builtin_amdgcn_s_sleep(4);
  }
  __syncthreads();
}

// ---- P3: fused tail: transposes+buildH | gcn0 | gcn1 | qkv | final ------
__global__ __launch_bounds__(256) void k_tail(
    const float* __restrict__ fts, const float* __restrict__ seg,
    const int* __restrict__ meta, const int* __restrict__ P,
    const float* __restrict__ g0, const float* __restrict__ g1,
    const float* __restrict__ qw, const float* __restrict__ kw,
    const float* __restrict__ vw, const float* __restrict__ mw,
    const float* __restrict__ gcn_b,
    const float* __restrict__ qb, const float* __restrict__ kb,
    const float* __restrict__ vb, const float* __restrict__ mapb,
    const float* __restrict__ gamma, const float* __restrict__ alpha,
    float* __restrict__ g0T, float* __restrict__ g1T, float* __restrict__ qwT,
    float* __restrict__ kwT, float* __restrict__ vwT, float* __restrict__ mwT,
    float* __restrict__ glob, float* __restrict__ HA, float* __restrict__ HB,
    float* __restrict__ HC, float* __restrict__ nsqA, float* __restrict__ nsqB,
    float* __restrict__ qv, float* __restrict__ kv, float* __restrict__ vv,
    float* __restrict__ out, int* __restrict__ bar) {
  int r = blockIdx.x;  // 0..50
  int t = threadIdx.x, lane = t & 63, w = t >> 6;
  __shared__ float tile[32][33];
  __shared__ float sHa[CDIM];
  __shared__ float sagg[CDIM];
  __shared__ float sadj[64];
  __shared__ float wsum[4];

  // ---- stage A1: weight transposes (1280 32x32 tiles over 51 blocks) ----
  for (int tid = r; tid < 1280; tid += NROWS) {
    const float* in; float* outp; int rows, cols, lt;
    if (tid < 256)       { in = g0; outp = g0T; rows = 512; cols = 512; lt = tid; }
    else if (tid < 512)  { in = g1; outp = g1T; rows = 512; cols = 512; lt = tid - 256; }
    else if (tid < 640)  { in = qw; outp = qwT; rows = 256; cols = 512; lt = tid - 512; }
    else if (tid < 768)  { in = kw; outp = kwT; rows = 256; cols = 512; lt = tid - 640; }
    else if (tid < 1024) { in = vw; outp = vwT; rows = 512; cols = 512; lt = tid - 768; }
    else                 { in = mw; outp = mwT; rows = 512; cols = 512; lt = tid - 1024; }
    int ctiles = cols / 32;
    int r0 = (lt / ctiles) * 32, c0 = (lt % ctiles) * 32;
    int tx = t & 31, ty = t >> 5;
#pragma unroll
    for (int j = 0; j < 4; ++j)
      tile[ty + j * 8][tx] = in[(size_t)(r0 + ty + j * 8) * cols + c0 + tx];
    __syncthreads();
#pragma unroll
    for (int j = 0; j < 4; ++j)
      outp[(size_t)(c0 + ty + j * 8) * rows + r0 + tx] = tile[tx][ty + j * 8];
    __syncthreads();
  }

  // ---- stage A2: build H row r, glob, nsq -------------------------------
  {
    int L = meta[0];
    float nl = 0.f;
#pragma unroll
    for (int half = 0; half < 2; ++half) {
      int c = t + half * 256;
      float h;
      if (r == 0) {
        float s = 0.f;
#pragma unroll 5
        for (int i = 0; i < NN; ++i) s += seg[i * CDIM + c];
        h = s / ((float)L + 1e-8f);
        glob[c] = h;
      } else {
        int i = r - 1;
        float s = seg[i * CDIM + c];
        if (meta[2 + 2 * NN + i]) s += fts[(size_t)c * HW + P[i]];
        h = s / fmaxf((float)meta[2 + NN + i], 1.f);
      }
      HA[r * CDIM + c] = h;
      nl += h * h;
    }
    nl = wave_sum(nl);
    if (lane == 0) wsum[w] = nl;
    __syncthreads();
    if (t == 0) nsqA[r] = wsum[0] + wsum[1] + wsum[2] + wsum[3];
  }
  gbar(bar, 0, NROWS);

  // ---- stages B, C: two GCN layers --------------------------------------
#pragma unroll 1
  for (int l = 0; l < 2; ++l) {
    const float* Hin = l ? HB : HA;
    float* Hout = l ? HC : HB;
    const float* nsq = l ? nsqB : nsqA;
    float* nsqOut = l ? nsqA : nsqB;  // nsqA reused for layer-1 output
    const float* WT = l ? g1T : g0T;
    const float* bias = gcn_b + l * CDIM;
    sHa[t] = Hin[r * CDIM + t];
    sHa[t + 256] = Hin[r * CDIM + t + 256];
    __syncthreads();
    float na = fmaxf(sqrtf(nsq[r]), 1e-12f);
    for (int b = w; b < NROWS; b += 4) {
      const float* hb = Hin + b * CDIM;
      float d = 0.f;
#pragma unroll
      for (int k = 0; k < 8; ++k) d += sHa[lane + k * 64] * hb[lane + k * 64];
      d = wave_sum(d);
      if (lane == 0) {
        float nb = fmaxf(sqrtf(nsq[b]), 1e-12f);
        sadj[b] = fmaxf(d / (na * nb), 0.f);
      }
    }
    __syncthreads();
    if (t < 64) {
      float sv = (t < NROWS) ? sadj[t] : -1e30f;
      float m = wave_max(sv);
      float e = (t < NROWS) ? expf(sv - m) : 0.f;
      float su = wave_sum(e);
      if (t < NROWS) sadj[t] = e / su;
    }
    __syncthreads();
#pragma unroll
    for (int half = 0; half < 2; ++half) {
      int c = t + half * 256;
      float acc = 0.f;
#pragma unroll 3
      for (int b = 0; b < NROWS; ++b) acc += sadj[b] * Hin[b * CDIM + c];
      sagg[c] = acc;
    }
    __syncthreads();
    float nl = 0.f;
#pragma unroll
    for (int half = 0; half < 2; ++half) {
      int c = t + half * 256;
      float acc = bias[c];
#pragma unroll 8
      for (int k = 0; k < CDIM; ++k) acc += sagg[k] * WT[k * CDIM + c];
      float h = sHa[c] + fmaxf(acc, 0.f);
      Hout[r * CDIM + c] = h;
      nl += h * h;
    }
    nl = wave_sum(nl);
    if (lane == 0) wsum[w] = nl;
    __syncthreads();
    if (t == 0) nsqOut[r] = wsum[0] + wsum[1] + wsum[2] + wsum[3];
    gbar(bar, 1 + l, NROWS);
  }

  // ---- stage D: q,k,v projections ---------------------------------------
  {
    sHa[t] = HC[r * CDIM + t];
    sHa[t + 256] = HC[r * CDIM + t + 256];
    __syncthreads();
    if (r == 0) {
      float acc = qb[t];
#pragma unroll 8
      for (int k = 0; k < CDIM; ++k) acc += sHa[k] * qwT[k * 256 + t];
      qv[t] = acc;
    } else {
      int i = r - 1;
      float acc = kb[t];
#pragma unroll 8
      for (int k = 0; k < CDIM; ++k) acc += sHa[k] * kwT[k * 256 + t];
      kv[i * 256 + t] = acc;
      float a0 = vb[t], a1 = vb[t + 256];
#pragma unroll 8
      for (int k = 0; k < CDIM; ++k) {
        float hv = sHa[k];
        a0 += hv * vwT[k * CDIM + t];
        a1 += hv * vwT[k * CDIM + t + 256];
      }
      vv[i * CDIM + t] = a0;
      vv[i * CDIM + t + 256] = a1;
    }
  }
  gbar(bar, 3, NROWS);
  if (r >= 4) return;

  // ---- stage E: attention + map + blend (blocks 0..3) -------------------
  for (int i = w; i < NN; i += 4) {
    float d = 0.f;
#pragma unroll
    for (int k = 0; k < 4; ++k) d += qv[lane + k * 64] * kv[i * 256 + lane + k * 64];
    d = wave_sum(d);
    if (lane == 0) sadj[i] = d * (1.f / 16.f);
  }
  __syncthreads();
  if (t < 64) {
    float sv = (t < NN) ? sadj[t] : -1e30f;
    float m = wave_max(sv);
    float e = (t < NN) ? expf(sv - m) : 0.f;
    float su = wave_sum(e);
    if (t < NN) sadj[t] = e / su;
  }
  __syncthreads();
#pragma unroll
  for (int half = 0; half < 2; ++half) {
    int c = t + half * 256;
    float acc = 0.f;
#pragma unroll 5
    for (int i = 0; i < NN; ++i) acc += sadj[i] * vv[i * CDIM + c];
    sagg[c] = acc;
  }
  __syncthreads();
  if (t < 128) {
    int c = r * 128 + t;
    float o = mapb[c];
#pragma unroll 8
    for (int k = 0; k < CDIM; ++k) o += sagg[k] * mwT[k * CDIM + c];
    float wv_ = 1.f / (1.f + expf(-alpha[0]));
    float fp = HC[c] + gamma[0] * o;
    out[c] = glob[c] * (1.f - wv_) + fp * wv_;
  }
}

// -------------------------------------------------------------------------
extern "C" void kernel_launch(void* const* d_in, const int* in_sizes, int n_in,
                              void* d_out, int out_size, void* d_ws, size_t ws_size,
                              hipStream_t stream) {
  const float* fts = (const float*)d_in[0];
  const int* msk = (const int*)d_in[1];
  const float* gcn_w = (const float*)d_in[2];
  const float* gcn_b = (const float*)d_in[3];
  const float* q_w = (const float*)d_in[4];
  const float* q_b = (const float*)d_in[5];
  const float* k_w = (const float*)d_in[6];
  const float* k_b = (const float*)d_in[7];
  const float* v_w = (const float*)d_in[8];
  const float* v_b = (const float*)d_in[9];
  const float* map_w = (const float*)d_in[10];
  const float* map_b = (const float*)d_in[11];
  const float* gamma = (const float*)d_in[12];
  const float* alpha = (const float*)d_in[13];
  float* out = (float*)d_out;

  char* wp = (char*)d_ws;
  auto alloc = [&](size_t bytes) {
    char* p = wp;
    wp += (bytes + 255) & ~(size_t)255;
    return p;
  };
  float* g0T = (float*)alloc(512 * 512 * 4);
  float* g1T = (float*)alloc(512 * 512 * 4);
  float* qwT = (float*)alloc(512 * 256 * 4);
  float* kwT = (float*)alloc(512 * 256 * 4);
  float* vwT = (float*)alloc(512 * 512 * 4);
  float* mwT = (float*)alloc(512 * 512 * 4);
  int* blkcnt = (int*)alloc(64 * 4);
  int* meta = (int*)alloc(160 * 4);
  int* P = (int*)alloc(NN * 4);
  unsigned char* bin8 = (unsigned char*)alloc(HW);
  float* seg = (float*)alloc(NN * CDIM * 4);
  float* glob = (float*)alloc(CDIM * 4);
  float* HA = (float*)alloc(NROWS * CDIM * 4);
  float* HB = (float*)alloc(NROWS * CDIM * 4);
  float* HC = (float*)alloc(NROWS * CDIM * 4);
  float* nsqA = (float*)alloc(NROWS * 4);
  float* nsqB = (float*)alloc(NROWS * 4);
  float* qv = (float*)alloc(256 * 4);
  float* kv = (float*)alloc(NN * 256 * 4);
  float* vv = (float*)alloc(NN * CDIM * 4);
  int* bar = (int*)alloc(8 * 4);

  k_prep<<<64, 256, 0, stream>>>(msk, blkcnt, seg, bar);
  k_rank<<<64, 256, 0, stream>>>(msk, blkcnt, meta, bin8, P);
  k_seg<<<dim3(128, 8), 256, 0, stream>>>(fts, bin8, seg);
  k_tail<<<NROWS, 256, 0, stream>>>(
      fts, seg, meta, P, gcn_w, gcn_w + 512 * 512, q_w, k_w, v_w, map_w,
      gcn_b, q_b, k_b, v_b, map_b, gamma, alpha,
      g0T, g1T, qwT, kwT, vwT, mwT, glob, HA, HB, HC, nsqA, nsqB,
      qv, kv, vv, out, bar);
}